// Round 3
// baseline (432.909 us; speedup 1.0000x reference)
//
#include <hip/hip_runtime.h>
#include <cstdint>

#define TPB 256

static constexpr float INV_SQRT_FAN = 0.08838834764831845f; // 1/sqrt(128)
static constexpr float INV_SQRT3_C  = 0.5773502691896258f;  // 1/sqrt(3)

typedef unsigned short u16x8 __attribute__((ext_vector_type(8)));
typedef unsigned short u16x4 __attribute__((ext_vector_type(4)));

// Plain-layout bf16 weights in a device global (written by prep each launch):
// [0,16384): W0b flat [k*128+n]; [16384,24576): W1b flat [k*64+o].
__device__ __align__(16) uint16_t g_wf[24576];

__device__ __forceinline__ uint16_t f2bf(float f) {
  uint32_t u = __float_as_uint(f);
  u += 0x7fffu + ((u >> 16) & 1u);
  return (uint16_t)(u >> 16);
}
__device__ __forceinline__ uint32_t pk2(float a, float b) {
  return (uint32_t)f2bf(a) | ((uint32_t)f2bf(b) << 16);
}
__device__ __forceinline__ float bf2f(unsigned short u) {
  return __uint_as_float(((uint32_t)u) << 16);
}

__global__ void prep_kernel(const float* __restrict__ W0,
                            const float* __restrict__ W1) {
  int id = blockIdx.x * TPB + threadIdx.x;  // [0, 24576)
  g_wf[id] = f2bf(id < 16384 ? W0[id] : W1[id - 16384]);
}

// VALU bisect kernel: same bf16 quantization of tp and W as the MFMA version,
// same epilogue formulas, same store pattern — only the matmul is plain fp32
// VALU accumulation with explicit indexing (no fragment-layout assumptions).
__global__ __launch_bounds__(TPB, 2) void tplg_valu(
    const float* __restrict__ x, const float* __restrict__ y,
    const float* __restrict__ b0, float* __restrict__ out) {
  // 64KB LDS map (uint16 units):
  //   [0,16384)      W0b [k][n]  (32KB)
  //   [16384,24576)  W1b [k][o]  (16KB)   -- later aliased: gates 16x64 f32
  //   [24576,32768)  tp  [r][m][k] 16 rows x 4 mats x 128k (16KB)
  //                                      -- later aliased: out-staging 16x256 f32
  __shared__ uint16_t lds16[32768];
  float* ldsf = (float*)lds16;

  const int t = threadIdx.x;
  const long rowBase = (long)blockIdx.x * 16;

  // ---- stage weights (global -> LDS), 3072 uint4 total ----
  {
    uint4* dst = (uint4*)lds16;
    const uint4* src = (const uint4*)g_wf;
    #pragma unroll
    for (int i = 0; i < 12; ++i) dst[i * 256 + t] = src[i * 256 + t];
  }

  // ---- stage tp (16 rows), bf16, layout [r][m][k] k-contiguous ----
  {
    const int u = t & 15;   // column slice [4u, 4u+4)
    const int r = t >> 4;   // row
    const float* xr = x + (rowBase + r) * 256;
    const float4 x0 = *(const float4*)(xr + 4 * u);
    const float4 aa = *(const float4*)(xr + 64 + 12 * u);
    const float4 bb = *(const float4*)(xr + 64 + 12 * u + 4);
    const float4 cc = *(const float4*)(xr + 64 + 12 * u + 8);
    const float4 yv = *(const float4*)(y + (rowBase + r) * 4);
    const float y0 = yv.x, y1 = yv.y, y2 = yv.z, y3 = yv.w;
    const float t0x = aa.x, t0y = aa.y, t0z = aa.z;
    const float t1x = aa.w, t1y = bb.x, t1z = bb.y;
    const float t2x = bb.z, t2y = bb.w, t2z = cc.x;
    const float t3x = cc.y, t3y = cc.z, t3z = cc.w;
    const int c0 = 4 * u;
    const int base = 24576 + r * 512;  // this row's tp block
    // m=0: tp0. low half k=c0..c0+3 = x0*y0
    *(uint2*)(lds16 + base + c0) =
        make_uint2(pk2(x0.x * y0, x0.y * y0), pk2(x0.z * y0, x0.w * y0));
    // m=0 high half k=64+c0.. = dot(x1[c], y1)*inv_sqrt3
    const float d0 = (t0x * y1 + t0y * y2 + t0z * y3) * INV_SQRT3_C;
    const float d1 = (t1x * y1 + t1y * y2 + t1z * y3) * INV_SQRT3_C;
    const float d2 = (t2x * y1 + t2y * y2 + t2z * y3) * INV_SQRT3_C;
    const float d3 = (t3x * y1 + t3y * y2 + t3z * y3) * INV_SQRT3_C;
    *(uint2*)(lds16 + base + 64 + c0) = make_uint2(pk2(d0, d1), pk2(d2, d3));
    // m=1..3: tp1_i low = x0*y1[i]; high = x1[c][i]*y0
    *(uint2*)(lds16 + base + 128 + c0) =
        make_uint2(pk2(x0.x * y1, x0.y * y1), pk2(x0.z * y1, x0.w * y1));
    *(uint2*)(lds16 + base + 128 + 64 + c0) =
        make_uint2(pk2(t0x * y0, t1x * y0), pk2(t2x * y0, t3x * y0));
    *(uint2*)(lds16 + base + 256 + c0) =
        make_uint2(pk2(x0.x * y2, x0.y * y2), pk2(x0.z * y2, x0.w * y2));
    *(uint2*)(lds16 + base + 256 + 64 + c0) =
        make_uint2(pk2(t0y * y0, t1y * y0), pk2(t2y * y0, t3y * y0));
    *(uint2*)(lds16 + base + 384 + c0) =
        make_uint2(pk2(x0.x * y3, x0.y * y3), pk2(x0.z * y3, x0.w * y3));
    *(uint2*)(lds16 + base + 384 + 64 + c0) =
        make_uint2(pk2(t0z * y0, t1z * y0), pk2(t2z * y0, t3z * y0));
  }
  __syncthreads();

  // ---- compute: thread = (row r, col-worker w) ----
  // s cols [8w, 8w+8);  v outputs o in [4w, 4w+4) x i in {0,1,2}
  const int r = t >> 4, w = t & 15;
  float sacc[8], vacc[12];
  #pragma unroll
  for (int i = 0; i < 8; ++i) sacc[i] = 0.f;
  #pragma unroll
  for (int i = 0; i < 12; ++i) vacc[i] = 0.f;

  const uint16_t* tpb = lds16 + 24576 + r * 512;
  for (int k8 = 0; k8 < 16; ++k8) {
    const u16x8 a0v = *(const u16x8*)(tpb + 0   + k8 * 8);
    const u16x8 a1v = *(const u16x8*)(tpb + 128 + k8 * 8);
    const u16x8 a2v = *(const u16x8*)(tpb + 256 + k8 * 8);
    const u16x8 a3v = *(const u16x8*)(tpb + 384 + k8 * 8);
    #pragma unroll
    for (int j = 0; j < 8; ++j) {
      const int k = k8 * 8 + j;
      const float a0 = bf2f(a0v[j]);
      const float a1 = bf2f(a1v[j]);
      const float a2 = bf2f(a2v[j]);
      const float a3 = bf2f(a3v[j]);
      const u16x8 w0v = *(const u16x8*)(lds16 + k * 128 + 8 * w);
      #pragma unroll
      for (int n = 0; n < 8; ++n) sacc[n] += a0 * bf2f(w0v[n]);
      const u16x4 w1v = *(const u16x4*)(lds16 + 16384 + k * 64 + 4 * w);
      #pragma unroll
      for (int o = 0; o < 4; ++o) {
        const float wv = bf2f(w1v[o]);
        vacc[o * 3 + 0] += a1 * wv;
        vacc[o * 3 + 1] += a2 * wv;
        vacc[o * 3 + 2] += a3 * wv;
      }
    }
  }
  __syncthreads();  // everyone done reading W/tp; alias regions now

  // ---- epilogue ----
  float* gatep = ldsf + 8192;   // 16 x 64 gates (aliases W1b)
  float* stg   = ldsf + 12288;  // 16 x 256 out-staging (aliases tp)
  if (w < 8) {
    #pragma unroll
    for (int n = 0; n < 8; ++n) {
      const int col = 8 * w + n;  // gate col [0,64)
      const float s = sacc[n] * INV_SQRT_FAN + b0[col];
      gatep[r * 64 + col] = __builtin_amdgcn_rcpf(1.0f + __expf(-s));
    }
  } else {
    #pragma unroll
    for (int n = 0; n < 8; ++n) {
      const int col = 8 * w + n;  // scalar col [64,128)
      const float s = sacc[n] * INV_SQRT_FAN + b0[col];
      const float u3 = s * s * s;
      const float ua = 0.7978845608028654f * (s + 0.044715f * u3);
      const float e = __expf(2.0f * ua);
      const float th = 1.0f - 2.0f * __builtin_amdgcn_rcpf(e + 1.0f);
      stg[r * 256 + (col - 64)] = 0.5f * s * (1.0f + th);
    }
  }
  __syncthreads();
  #pragma unroll
  for (int o4 = 0; o4 < 4; ++o4) {
    const int o = 4 * w + o4;
    const float g = gatep[r * 64 + o];
    #pragma unroll
    for (int i = 0; i < 3; ++i) {
      stg[r * 256 + 64 + o * 3 + i] = g * vacc[o4 * 3 + i] * INV_SQRT_FAN;
    }
  }
  __syncthreads();

  // ---- coalesced store: 16 rows x 256 f32 = 1024 float4 ----
  const float4* s4 = (const float4*)stg;
  float4* o4p = (float4*)(out + rowBase * 256);
  #pragma unroll
  for (int i = 0; i < 4; ++i) o4p[i * 256 + t] = s4[i * 256 + t];
}

extern "C" void kernel_launch(void* const* d_in, const int* in_sizes, int n_in,
                              void* d_out, int out_size, void* d_ws, size_t ws_size,
                              hipStream_t stream) {
  const float* x  = (const float*)d_in[0];
  const float* y  = (const float*)d_in[1];
  const float* W0 = (const float*)d_in[2];
  const float* b0 = (const float*)d_in[3];
  const float* W1 = (const float*)d_in[4];
  float* out = (float*)d_out;
  (void)d_ws; (void)ws_size;

  const int rows = in_sizes[0] / 256;  // 131072
  prep_kernel<<<24576 / TPB, TPB, 0, stream>>>(W0, W1);
  tplg_valu<<<rows / 16, TPB, 0, stream>>>(x, y, b0, out);
}